// Round 4
// baseline (2035.358 us; speedup 1.0000x reference)
//
#include <hip/hip_runtime.h>
#include <cstdint>
#include <cstddef>

// ---------------------------------------------------------------------------
// TopoGNN: 3x SAGEConv(mean) + BN + ReLU, softmax-attention pooling, 2 heads.
// N=100000 nodes, E=1600000 edges, B=64 segments, IN_CH=6, HID=64.
// R1: scatter atomics -> CSR pull. R2: multi-block scan, 2-node matmul.
// R3: exact-CSR scatter (105MB write amp, 128us) -> 256-node dst-bucket
//     partition (3-phase radix, zero global atomics in placement) + per-bucket
//     LDS-tile aggregation (ds_add_f32, conflict-free); degree + layer-1
//     matmul fused into the bucket kernel. Kills hist/scan/scatter/aggpull.
// ---------------------------------------------------------------------------

#define EPB 8192   // edges per partition block (256 thr x 32)
#define NBIN 512   // padded bucket count (actual NB = ceil(N/256) <= 512)

// ---- phase A: per-block bucket histogram ---------------------------------
__global__ __launch_bounds__(256) void bucket_hist(const int* __restrict__ dst,
                                                   int* __restrict__ blockBin,
                                                   int* __restrict__ binTotal, int E)
{
    __shared__ int hist[NBIN];
    int t = threadIdx.x;
    for (int i = t; i < NBIN; i += 256) hist[i] = 0;
    __syncthreads();
    int e0 = blockIdx.x * EPB;
#pragma unroll
    for (int k = 0; k < 32; k++) {
        int e = e0 + (k << 8) + t;
        if (e < E) atomicAdd(&hist[dst[e] >> 8], 1);
    }
    __syncthreads();
    for (int i = t; i < NBIN; i += 256) {
        int c = hist[i];
        blockBin[blockIdx.x * NBIN + i] = c;
        if (c) atomicAdd(&binTotal[i], c);
    }
}

// ---- phase B: scan bin totals; convert blockBin counts -> absolute offsets
__global__ __launch_bounds__(512) void bin_scan(const int* __restrict__ binTotal,
                                                int* __restrict__ binBase,
                                                int* __restrict__ blockBin, int nBlk)
{
    __shared__ int s[NBIN];
    int t = threadIdx.x;
    int tot = binTotal[t];
    s[t] = tot;
    __syncthreads();
    for (int off = 1; off < NBIN; off <<= 1) {
        int v = (t >= off) ? s[t - off] : 0;
        __syncthreads();
        s[t] += v;
        __syncthreads();
    }
    int excl = s[t] - tot;
    binBase[t] = excl;
    if (t == NBIN - 1) binBase[NBIN] = s[NBIN - 1];
    int run = excl;
    for (int blk = 0; blk < nBlk; blk++) {      // coalesced across t per blk step
        int idx = blk * NBIN + t;
        int c = blockBin[idx];
        blockBin[idx] = run;
        run += c;
    }
}

// ---- phase C: place (src,dst) pairs; per-block LDS cursors, no global atomics
__global__ __launch_bounds__(256) void bucket_scatter(const int* __restrict__ src,
                                                      const int* __restrict__ dst,
                                                      const int* __restrict__ blockBin,
                                                      int2* __restrict__ epair, int E)
{
    __shared__ int cur[NBIN];
    int t = threadIdx.x;
    for (int i = t; i < NBIN; i += 256) cur[i] = blockBin[blockIdx.x * NBIN + i];
    __syncthreads();
    int e0 = blockIdx.x * EPB;
#pragma unroll
    for (int k = 0; k < 32; k++) {
        int e = e0 + (k << 8) + t;
        if (e < E) {
            int d = dst[e];
            int pos = atomicAdd(&cur[d >> 8], 1);
            epair[pos] = make_int2(src[e], d);
        }
    }
}

// ---- layer 1: bucket LDS agg (6 ch) + degree count + fused matmul --------
__global__ __launch_bounds__(256) void sage1_bucket(
    const int2* __restrict__ epair, const int* __restrict__ binBase,
    const float* __restrict__ x,
    const float* __restrict__ Wl, const float* __restrict__ bias,
    const float* __restrict__ Wr,
    float* __restrict__ deg, float* __restrict__ out, int N)
{
    __shared__ float  a6[256 * 6];
    __shared__ int    cnt[256];
    __shared__ float4 sWl[6 * 16];
    __shared__ float4 sWr[6 * 16];
    int t = threadIdx.x;
    for (int i = t; i < 1536; i += 256) a6[i] = 0.f;
    cnt[t] = 0;
    if (t < 96) { sWl[t] = ((const float4*)Wl)[t]; sWr[t] = ((const float4*)Wr)[t]; }
    __syncthreads();

    int bkt  = blockIdx.x;
    int ebeg = binBase[bkt], eend = binBase[bkt + 1];
    for (int j = ebeg + t; j < eend; j += 256) {
        int2 p = epair[j];
        int dl = p.y & 255;
        const float2* r = (const float2*)(x + (size_t)p.x * 6);
        float2 r0 = r[0], r1 = r[1], r2 = r[2];
        atomicAdd(&a6[dl * 6 + 0], r0.x); atomicAdd(&a6[dl * 6 + 1], r0.y);
        atomicAdd(&a6[dl * 6 + 2], r1.x); atomicAdd(&a6[dl * 6 + 3], r1.y);
        atomicAdd(&a6[dl * 6 + 4], r2.x); atomicAdd(&a6[dl * 6 + 5], r2.y);
        atomicAdd(&cnt[dl], 1);
    }
    __syncthreads();

    int nb0  = bkt << 8;
    int node = nb0 + t;
    if (node >= N) return;

    float dg = (float)cnt[t];
    deg[node] = dg;
    float invd = 1.0f / fmaxf(dg, 1.0f);

    float a[6];
#pragma unroll
    for (int c = 0; c < 6; c++) a[c] = a6[t * 6 + c] * invd;

    const float2* xr2 = (const float2*)(x + (size_t)node * 6);
    float2 x0 = xr2[0], x1 = xr2[1], x2 = xr2[2];
    float hh[6] = {x0.x, x0.y, x1.x, x1.y, x2.x, x2.y};

    float4 acc[16];
#pragma unroll
    for (int cg = 0; cg < 16; cg++) acc[cg] = ((const float4*)bias)[cg];
#pragma unroll
    for (int k = 0; k < 6; k++) {
        float am = a[k], hk = hh[k];
#pragma unroll
        for (int cg = 0; cg < 16; cg++) {
            float4 wl = sWl[k * 16 + cg];
            float4 wr = sWr[k * 16 + cg];
            acc[cg].x = fmaf(am, wl.x, fmaf(hk, wr.x, acc[cg].x));
            acc[cg].y = fmaf(am, wl.y, fmaf(hk, wr.y, acc[cg].y));
            acc[cg].z = fmaf(am, wl.z, fmaf(hk, wr.z, acc[cg].z));
            acc[cg].w = fmaf(am, wl.w, fmaf(hk, wr.w, acc[cg].w));
        }
    }
    float4* orow = (float4*)(out + (size_t)node * 64);
#pragma unroll
    for (int cg = 0; cg < 16; cg++) orow[cg] = acc[cg];
}

// ---- layers 2/3: bucket LDS-tile aggregation (64 ch, lane = channel) ------
__global__ __launch_bounds__(256) void agg64_bucket(
    const int2* __restrict__ epair, const int* __restrict__ binBase,
    const float* __restrict__ h, float* __restrict__ agg, int N)
{
    __shared__ float sh[256 * 64];          // 64 KB -> 2 blocks/CU
    float4* sh4 = (float4*)sh;
    int t = threadIdx.x;
#pragma unroll
    for (int i = t; i < 4096; i += 256) sh4[i] = make_float4(0.f, 0.f, 0.f, 0.f);
    __syncthreads();

    int bkt  = blockIdx.x;
    int ebeg = binBase[bkt], eend = binBase[bkt + 1];
    int lane = t & 63, w = t >> 6;
    int nE = eend - ebeg;
    int G  = nE >> 3;                        // groups of 8 edges
    for (int g = w; g < G; g += 4) {
        int j = ebeg + g * 8;
#pragma unroll
        for (int u = 0; u < 8; u++) {
            int2  p = epair[j + u];
            float v = h[(size_t)p.x * 64 + lane];
            atomicAdd(&sh[(p.y & 255) * 64 + lane], v);   // ds_add_f32, 2-way alias: free
        }
    }
    if (w == 0) {
        for (int j = ebeg + (G << 3); j < eend; j++) {
            int2  p = epair[j];
            float v = h[(size_t)p.x * 64 + lane];
            atomicAdd(&sh[(p.y & 255) * 64 + lane], v);
        }
    }
    __syncthreads();

    int nb0 = bkt << 8;
    int count = min(256, N - nb0);
    float4* out4 = (float4*)(agg + (size_t)nb0 * 64);
    for (int i = t; i < count * 16; i += 256) out4[i] = sh4[i];
}

// out[i][:] = (agg[i]/max(deg,1)) @ Wl + bias + hin[i] @ Wr, 2 nodes/thread
__global__ __launch_bounds__(256) void sage_matmul64(
    const float* __restrict__ agg, const float* __restrict__ hin,
    const float* __restrict__ deg, const float* __restrict__ Wl,
    const float* __restrict__ bias, const float* __restrict__ Wr,
    float* __restrict__ out, int n)
{
    __shared__ float4 sWl[64 * 16];
    __shared__ float4 sWr[64 * 16];
    for (int i = threadIdx.x; i < 64 * 16; i += 256) {
        sWl[i] = ((const float4*)Wl)[i];
        sWr[i] = ((const float4*)Wr)[i];
    }
    __syncthreads();

    int node0 = blockIdx.x * 512 + threadIdx.x;
    if (node0 >= n) return;
    int  node1 = node0 + 256;
    bool has1  = (node1 < n);
    int  n1    = has1 ? node1 : node0;

    float invd0 = 1.0f / fmaxf(deg[node0], 1.0f);
    float invd1 = 1.0f / fmaxf(deg[n1], 1.0f);

    float4 acc0[16], acc1[16];
#pragma unroll
    for (int cg = 0; cg < 16; cg++) {
        float4 bv = ((const float4*)bias)[cg];
        acc0[cg] = bv;
        acc1[cg] = bv;
    }

    const float4* ar0 = (const float4*)(agg + (size_t)node0 * 64);
    const float4* hr0 = (const float4*)(hin + (size_t)node0 * 64);
    const float4* ar1 = (const float4*)(agg + (size_t)n1 * 64);
    const float4* hr1 = (const float4*)(hin + (size_t)n1 * 64);

#pragma unroll 1   // keep body ~10KB: fits L1I; inner j/cg fully unrolled
    for (int k4 = 0; k4 < 16; k4++) {
        float4 a0 = ar0[k4], h0 = hr0[k4];
        float4 a1 = ar1[k4], h1 = hr1[k4];
        float aa0[4] = {a0.x, a0.y, a0.z, a0.w}, hh0[4] = {h0.x, h0.y, h0.z, h0.w};
        float aa1[4] = {a1.x, a1.y, a1.z, a1.w}, hh1[4] = {h1.x, h1.y, h1.z, h1.w};
#pragma unroll
        for (int j = 0; j < 4; j++) {
            float am0 = aa0[j] * invd0, hk0 = hh0[j];
            float am1 = aa1[j] * invd1, hk1 = hh1[j];
            int k = k4 * 4 + j;
#pragma unroll
            for (int cg = 0; cg < 16; cg++) {
                float4 wl = sWl[k * 16 + cg];
                float4 wr = sWr[k * 16 + cg];
                acc0[cg].x = fmaf(am0, wl.x, fmaf(hk0, wr.x, acc0[cg].x));
                acc0[cg].y = fmaf(am0, wl.y, fmaf(hk0, wr.y, acc0[cg].y));
                acc0[cg].z = fmaf(am0, wl.z, fmaf(hk0, wr.z, acc0[cg].z));
                acc0[cg].w = fmaf(am0, wl.w, fmaf(hk0, wr.w, acc0[cg].w));
                acc1[cg].x = fmaf(am1, wl.x, fmaf(hk1, wr.x, acc1[cg].x));
                acc1[cg].y = fmaf(am1, wl.y, fmaf(hk1, wr.y, acc1[cg].y));
                acc1[cg].z = fmaf(am1, wl.z, fmaf(hk1, wr.z, acc1[cg].z));
                acc1[cg].w = fmaf(am1, wl.w, fmaf(hk1, wr.w, acc1[cg].w));
            }
        }
    }
    float4* o0 = (float4*)(out + (size_t)node0 * 64);
#pragma unroll
    for (int cg = 0; cg < 16; cg++) o0[cg] = acc0[cg];
    if (has1) {
        float4* o1 = (float4*)(out + (size_t)node1 * 64);
#pragma unroll
        for (int cg = 0; cg < 16; cg++) o1[cg] = acc1[cg];
    }
}

// ---- BatchNorm ------------------------------------------------------------

__global__ __launch_bounds__(256) void bn_stats(const float* __restrict__ h,
                                                float* __restrict__ stats, size_t total)
{
    __shared__ float ls[64], lss[64];
    if (threadIdx.x < 64) { ls[threadIdx.x] = 0.f; lss[threadIdx.x] = 0.f; }
    __syncthreads();
    float s = 0.f, ss = 0.f;
    size_t stride = (size_t)gridDim.x * 256;
    for (size_t i = (size_t)blockIdx.x * 256 + threadIdx.x; i < total; i += stride) {
        float v = h[i];
        s += v;
        ss = fmaf(v, v, ss);
    }
    int c = threadIdx.x & 63;
    atomicAdd(&ls[c], s);
    atomicAdd(&lss[c], ss);
    __syncthreads();
    if (threadIdx.x < 64) {
        unsafeAtomicAdd(&stats[threadIdx.x], ls[threadIdx.x]);
        unsafeAtomicAdd(&stats[64 + threadIdx.x], lss[threadIdx.x]);
    }
}

__global__ __launch_bounds__(256) void bn_relu(float* __restrict__ h,
                                               const float* __restrict__ stats,
                                               const float* __restrict__ g,
                                               const float* __restrict__ be,
                                               float inv_n, size_t total)
{
    size_t i = (size_t)blockIdx.x * 256 + threadIdx.x;
    if (i >= total) return;
    int   c   = threadIdx.x & 63;
    float mu  = stats[c] * inv_n;
    float var = stats[64 + c] * inv_n - mu * mu;
    float sc  = g[c] / sqrtf(var + 1e-5f);
    float sh  = fmaf(-mu, sc, be[c]);
    h[i] = fmaxf(fmaf(h[i], sc, sh), 0.f);
}

// ---- pooling + heads ------------------------------------------------------

__global__ __launch_bounds__(256) void softmax_sum(const float* __restrict__ x,
                                                   float* __restrict__ sumexp, int n)
{
    float s = 0.f;
    int stride = gridDim.x * 256;
    for (int i = blockIdx.x * 256 + threadIdx.x; i < n; i += stride)
        s += expf(x[(size_t)i * 6 + 4]);
#pragma unroll
    for (int o = 32; o > 0; o >>= 1) s += __shfl_down(s, o, 64);
    __shared__ float wsum[4];
    if ((threadIdx.x & 63) == 0) wsum[threadIdx.x >> 6] = s;
    __syncthreads();
    if (threadIdx.x == 0)
        unsafeAtomicAdd(sumexp, wsum[0] + wsum[1] + wsum[2] + wsum[3]);
}

__global__ void seg_bounds(const int* __restrict__ batch, int* __restrict__ lb, int n)
{
    int b = threadIdx.x;
    if (b > 64) return;
    int lo = 0, hi = n;
    while (lo < hi) {
        int mid = (lo + hi) >> 1;
        if (batch[mid] < b) lo = mid + 1; else hi = mid;
    }
    lb[b] = lo;
}

__global__ __launch_bounds__(256) void pool_kernel(const float* __restrict__ h,
                                                   const float* __restrict__ x,
                                                   const int* __restrict__ lb,
                                                   const float* __restrict__ sumexp,
                                                   float* __restrict__ pool, int n)
{
    int b = blockIdx.x;
    int start = lb[b], end = lb[b + 1];
    int c = threadIdx.x & 63, grp = threadIdx.x >> 6;
    float inv_se = 1.0f / sumexp[0];
    float acc = 0.f;
    for (int i = start + grp; i < end; i += 4) {
        float w = expf(x[(size_t)i * 6 + 4]) * inv_se;
        acc = fmaf(h[(size_t)i * 64 + c], w, acc);
    }
    __shared__ float red[4][64];
    red[grp][c] = acc;
    __syncthreads();
    if (grp == 0) {
        float cnt = (float)(end - start);
        pool[b * 64 + c] = (red[0][c] + red[1][c] + red[2][c] + red[3][c]) / fmaxf(cnt, 1.0f);
    }
}

__global__ __launch_bounds__(64) void heads_kernel(
    const float* __restrict__ pool,
    const float* __restrict__ phW1, const float* __restrict__ phb1,
    const float* __restrict__ phW2, const float* __restrict__ phb2,
    const float* __restrict__ trW1, const float* __restrict__ trb1,
    const float* __restrict__ trW2, const float* __restrict__ trb2,
    float* __restrict__ out)
{
    int b = blockIdx.x, t = threadIdx.x;
    __shared__ float p[64], h1[32], h2[16];
    p[t] = pool[b * 64 + t];
    __syncthreads();
    if (t < 32) {
        float s = phb1[t];
        for (int k = 0; k < 64; k++) s = fmaf(p[k], phW1[k * 32 + t], s);
        h1[t] = fmaxf(s, 0.f);
    } else if (t < 48) {
        int tt = t - 32;
        float s = trb1[tt];
        for (int k = 0; k < 64; k++) s = fmaf(p[k], trW1[k * 16 + tt], s);
        h2[tt] = fmaxf(s, 0.f);
    }
    __syncthreads();
    if (t < 3) {
        float s = phb2[t];
        for (int k = 0; k < 32; k++) s = fmaf(h1[k], phW2[k * 3 + t], s);
        out[b * 3 + t] = s;
    } else if (t == 63) {
        float s = trb2[0];
        for (int k = 0; k < 16; k++) s = fmaf(h2[k], trW2[k], s);
        out[192 + b] = 1.0f / (1.0f + expf(-s));
    }
}

extern "C" void kernel_launch(void* const* d_in, const int* in_sizes, int n_in,
                              void* d_out, int out_size, void* d_ws, size_t ws_size,
                              hipStream_t stream)
{
    const float* x     = (const float*)d_in[0];
    const int*   ei    = (const int*)d_in[1];
    const int*   batch = (const int*)d_in[2];
    const float* W1l = (const float*)d_in[3];
    const float* b1  = (const float*)d_in[4];
    const float* W1r = (const float*)d_in[5];
    const float* W2l = (const float*)d_in[6];
    const float* b2  = (const float*)d_in[7];
    const float* W2r = (const float*)d_in[8];
    const float* W3l = (const float*)d_in[9];
    const float* b3  = (const float*)d_in[10];
    const float* W3r = (const float*)d_in[11];
    const float* g1  = (const float*)d_in[12];
    const float* be1 = (const float*)d_in[13];
    const float* g2  = (const float*)d_in[14];
    const float* be2 = (const float*)d_in[15];
    const float* g3  = (const float*)d_in[16];
    const float* be3 = (const float*)d_in[17];
    const float* phW1 = (const float*)d_in[18];
    const float* phb1 = (const float*)d_in[19];
    const float* phW2 = (const float*)d_in[20];
    const float* phb2 = (const float*)d_in[21];
    const float* trW1 = (const float*)d_in[22];
    const float* trb1 = (const float*)d_in[23];
    const float* trW2 = (const float*)d_in[24];
    const float* trb2 = (const float*)d_in[25];

    const int N = in_sizes[0] / 6;
    const int E = in_sizes[1] / 2;
    const int* src = ei;
    const int* dst = ei + E;

    const int NB    = (N + 255) >> 8;          // 391 buckets
    const int nBlkA = (E + EPB - 1) / EPB;     // 196 partition blocks

    float* ws = (float*)d_ws;
    const size_t N64 = (size_t)N * 64;
    float* agg      = ws;                          // N*64
    float* hA       = ws + N64;                    // N*64
    float* hB       = ws + 2 * N64;                // N*64
    float* deg      = ws + 3 * N64;                // N (N even -> epair 8B-aligned)
    int2*  epair    = (int2*)(deg + N);            // E pairs
    int*   blockBin = (int*)(epair + E);           // nBlkA * NBIN
    // --- contiguous zero region: binTotal + stats[3][128] + sumexp ---
    int*   binTotal = blockBin + (size_t)nBlkA * NBIN;   // NBIN
    float* stats    = (float*)(binTotal + NBIN);   // 3 * 128
    float* sumexp   = stats + 384;                 // 1 (pad 4)
    // --- end zero region ---
    int*   binBase  = (int*)(sumexp + 4);          // NBIN + 1
    int*   lb       = binBase + NBIN + 1;          // 65 (pad 72)
    float* pool     = (float*)(lb + 72);           // 64*64
    float* out      = (float*)d_out;

    const int ewBlocks  = (int)((N64 + 255) / 256);
    const int mm2Blocks = (N + 511) / 512;
    const float invN = 1.0f / (float)N;

    // ---- edge partition into 256-node dst buckets ----
    size_t zbytes = (char*)(sumexp + 4) - (char*)binTotal;
    hipMemsetAsync(binTotal, 0, zbytes, stream);
    bucket_hist<<<nBlkA, 256, 0, stream>>>(dst, blockBin, binTotal, E);
    bin_scan<<<1, NBIN, 0, stream>>>(binTotal, binBase, blockBin, nBlkA);
    bucket_scatter<<<nBlkA, 256, 0, stream>>>(src, dst, blockBin, epair, E);

    // ---- layer 1 (bucket agg 6ch + degree + fused matmul) ----
    sage1_bucket<<<NB, 256, 0, stream>>>(epair, binBase, x, W1l, b1, W1r, deg, hA, N);
    bn_stats<<<1024, 256, 0, stream>>>(hA, stats, N64);
    bn_relu<<<ewBlocks, 256, 0, stream>>>(hA, stats, g1, be1, invN, N64);

    // ---- layer 2 ----
    agg64_bucket<<<NB, 256, 0, stream>>>(epair, binBase, hA, agg, N);
    sage_matmul64<<<mm2Blocks, 256, 0, stream>>>(agg, hA, deg, W2l, b2, W2r, hB, N);
    bn_stats<<<1024, 256, 0, stream>>>(hB, stats + 128, N64);
    bn_relu<<<ewBlocks, 256, 0, stream>>>(hB, stats + 128, g2, be2, invN, N64);

    // ---- layer 3 ----
    agg64_bucket<<<NB, 256, 0, stream>>>(epair, binBase, hB, agg, N);
    sage_matmul64<<<mm2Blocks, 256, 0, stream>>>(agg, hB, deg, W3l, b3, W3r, hA, N);
    bn_stats<<<1024, 256, 0, stream>>>(hA, stats + 256, N64);
    bn_relu<<<ewBlocks, 256, 0, stream>>>(hA, stats + 256, g3, be3, invN, N64);

    // ---- attention pooling + heads ----
    softmax_sum<<<256, 256, 0, stream>>>(x, sumexp, N);
    seg_bounds<<<1, 128, 0, stream>>>(batch, lb, N);
    pool_kernel<<<64, 256, 0, stream>>>(hA, x, lb, sumexp, pool, N);
    heads_kernel<<<64, 64, 0, stream>>>(pool, phW1, phb1, phW2, phb2,
                                        trW1, trb1, trW2, trb2, out);
}

// Round 5
// 753.801 us; speedup vs baseline: 2.7001x; 2.7001x over previous
//
#include <hip/hip_runtime.h>
#include <cstdint>
#include <cstddef>

// ---------------------------------------------------------------------------
// TopoGNN: 3x SAGEConv(mean) + BN + ReLU, softmax-attention pooling, 2 heads.
// N=100000 nodes, E=1600000 edges, B=64 segments, IN_CH=6, HID=64.
// R1: scatter atomics -> CSR pull. R2: multi-block scan, 2-node matmul.
// R3: 858us; exact-CSR scatter had 105MB write-amp (128us).
// R4 FAILED: per-bucket LDS-tile aggregation -> 2 blocks/CU, 12.7% occupancy,
//     latency-bound gathers (686us/dispatch). Partition phases were cheap.
// R5: aggregation reverted to high-occupancy register pull (aggpull64);
//     CSR built via packed bucket partition + per-bucket local scatter into
//     the bucket's contiguous CSR region (writes stay in L2, ~1x write amp).
// ---------------------------------------------------------------------------

#define EPB 8192   // edges per partition block (256 thr x 32)
#define NBIN 512   // padded bucket count (actual NB = ceil(N/256) <= 512)

// ---- phase A: per-block bucket histogram ---------------------------------
__global__ __launch_bounds__(256) void bucket_hist(const int* __restrict__ dst,
                                                   int* __restrict__ blockBin,
                                                   int* __restrict__ binTotal, int E)
{
    __shared__ int hist[NBIN];
    int t = threadIdx.x;
    for (int i = t; i < NBIN; i += 256) hist[i] = 0;
    __syncthreads();
    int e0 = blockIdx.x * EPB;
#pragma unroll
    for (int k = 0; k < 32; k++) {
        int e = e0 + (k << 8) + t;
        if (e < E) atomicAdd(&hist[dst[e] >> 8], 1);
    }
    __syncthreads();
    for (int i = t; i < NBIN; i += 256) {
        int c = hist[i];
        blockBin[blockIdx.x * NBIN + i] = c;
        if (c) atomicAdd(&binTotal[i], c);
    }
}

// ---- phase B: scan bin totals -> binBase; blockBin counts -> abs offsets;
//      also writes rowptr[N] = E.
__global__ __launch_bounds__(512) void bin_scan(const int* __restrict__ binTotal,
                                                int* __restrict__ binBase,
                                                int* __restrict__ blockBin,
                                                int* __restrict__ rowptrN, int nBlk)
{
    __shared__ int s[NBIN];
    int t = threadIdx.x;
    int tot = binTotal[t];
    s[t] = tot;
    __syncthreads();
    for (int off = 1; off < NBIN; off <<= 1) {
        int v = (t >= off) ? s[t - off] : 0;
        __syncthreads();
        s[t] += v;
        __syncthreads();
    }
    int excl = s[t] - tot;
    binBase[t] = excl;
    if (t == NBIN - 1) { binBase[NBIN] = s[t]; *rowptrN = s[t]; }
    int run = excl;
    for (int blk = 0; blk < nBlk; blk++) {      // thread t walks bin t across blocks
        int idx = blk * NBIN + t;
        int c = blockBin[idx];
        blockBin[idx] = run;
        run += c;
    }
}

// ---- phase C: place packed (src | local_dst<<24); per-block LDS cursors ---
__global__ __launch_bounds__(256) void bucket_scatter(const int* __restrict__ src,
                                                      const int* __restrict__ dst,
                                                      const int* __restrict__ blockBin,
                                                      int* __restrict__ epck, int E)
{
    __shared__ int cur[NBIN];
    int t = threadIdx.x;
    for (int i = t; i < NBIN; i += 256) cur[i] = blockBin[blockIdx.x * NBIN + i];
    __syncthreads();
    int e0 = blockIdx.x * EPB;
#pragma unroll
    for (int k = 0; k < 32; k++) {
        int e = e0 + (k << 8) + t;
        if (e < E) {
            int d = dst[e];
            int pos = atomicAdd(&cur[d >> 8], 1);
            epck[pos] = src[e] | ((d & 255) << 24);   // src < 2^24
        }
    }
}

// ---- phase D: per-bucket local CSR: hist -> scan -> scatter into the
//      bucket's contiguous eidx region; rowptr from the same scan.
__global__ __launch_bounds__(256) void csr_local(const int* __restrict__ epck,
                                                 const int* __restrict__ binBase,
                                                 int* __restrict__ rowptr,
                                                 int* __restrict__ eidx, int N)
{
    __shared__ int cnt[256], s[256], cur[256];
    int t = threadIdx.x, bkt = blockIdx.x;
    int base = binBase[bkt], nE = binBase[bkt + 1] - base;
    cnt[t] = 0;
    __syncthreads();
    for (int j = t; j < nE; j += 256)
        atomicAdd(&cnt[(unsigned)epck[base + j] >> 24], 1);
    __syncthreads();
    s[t] = cnt[t];
    __syncthreads();
    for (int off = 1; off < 256; off <<= 1) {
        int v = (t >= off) ? s[t - off] : 0;
        __syncthreads();
        s[t] += v;
        __syncthreads();
    }
    int excl = s[t] - cnt[t];
    cur[t] = excl;
    int node = (bkt << 8) + t;
    if (node < N) rowptr[node] = base + excl;
    __syncthreads();
    for (int j = t; j < nE; j += 256) {
        int v = epck[base + j];
        int pos = atomicAdd(&cur[(unsigned)v >> 24], 1);
        eidx[base + pos] = v & 0xFFFFFF;     // 16KB span per block: stays in L2
    }
}

// ---- layer 1: fused pull-aggregation (6 ch) + matmul ----------------------
__global__ __launch_bounds__(256) void sage1_fused(
    const int* __restrict__ rowptr, const int* __restrict__ eidx,
    const float* __restrict__ x,
    const float* __restrict__ Wl, const float* __restrict__ bias,
    const float* __restrict__ Wr, float* __restrict__ out, int n)
{
    __shared__ float4 sWl[6 * 16];
    __shared__ float4 sWr[6 * 16];
    for (int i = threadIdx.x; i < 6 * 16; i += 256) {
        sWl[i] = ((const float4*)Wl)[i];
        sWr[i] = ((const float4*)Wr)[i];
    }
    __syncthreads();

    int node = blockIdx.x * 256 + threadIdx.x;
    if (node >= n) return;

    int b = rowptr[node], e = rowptr[node + 1];
    float a[6] = {0.f, 0.f, 0.f, 0.f, 0.f, 0.f};
    for (int j = b; j < e; j++) {
        int s = eidx[j];
        const float2* r = (const float2*)(x + (size_t)s * 6);
        float2 r0 = r[0], r1 = r[1], r2 = r[2];
        a[0] += r0.x; a[1] += r0.y; a[2] += r1.x;
        a[3] += r1.y; a[4] += r2.x; a[5] += r2.y;
    }
    float invd = 1.0f / fmaxf((float)(e - b), 1.0f);

    const float2* xr2 = (const float2*)(x + (size_t)node * 6);
    float2 x0 = xr2[0], x1 = xr2[1], x2 = xr2[2];
    float hh[6] = {x0.x, x0.y, x1.x, x1.y, x2.x, x2.y};

    float4 acc[16];
#pragma unroll
    for (int cg = 0; cg < 16; cg++) acc[cg] = ((const float4*)bias)[cg];
#pragma unroll
    for (int k = 0; k < 6; k++) {
        float am = a[k] * invd;
        float hk = hh[k];
#pragma unroll
        for (int cg = 0; cg < 16; cg++) {
            float4 wl = sWl[k * 16 + cg];
            float4 wr = sWr[k * 16 + cg];
            acc[cg].x = fmaf(am, wl.x, fmaf(hk, wr.x, acc[cg].x));
            acc[cg].y = fmaf(am, wl.y, fmaf(hk, wr.y, acc[cg].y));
            acc[cg].z = fmaf(am, wl.z, fmaf(hk, wr.z, acc[cg].z));
            acc[cg].w = fmaf(am, wl.w, fmaf(hk, wr.w, acc[cg].w));
        }
    }
    float4* orow = (float4*)(out + (size_t)node * 64);
#pragma unroll
    for (int cg = 0; cg < 16; cg++) orow[cg] = acc[cg];
}

// ---- 64-ch pull aggregation: one wave per node, lane = channel ------------
__global__ __launch_bounds__(256) void aggpull64(const int* __restrict__ rowptr,
                                                 const int* __restrict__ eidx,
                                                 const float* __restrict__ h,
                                                 float* __restrict__ agg, int n)
{
    int w    = (blockIdx.x * 256 + threadIdx.x) >> 6;
    int lane = threadIdx.x & 63;
    if (w >= n) return;
    int b = rowptr[w], e = rowptr[w + 1];
    float acc0 = 0.f, acc1 = 0.f, acc2 = 0.f, acc3 = 0.f;
    for (int j0 = b; j0 < e; j0 += 64) {
        int myidx = (j0 + lane < e) ? eidx[j0 + lane] : 0;
        int m = min(64, e - j0);
        int jj = 0;
        for (; jj + 4 <= m; jj += 4) {
            int s0 = __shfl(myidx, jj,     64);
            int s1 = __shfl(myidx, jj + 1, 64);
            int s2 = __shfl(myidx, jj + 2, 64);
            int s3 = __shfl(myidx, jj + 3, 64);
            acc0 += h[(size_t)s0 * 64 + lane];
            acc1 += h[(size_t)s1 * 64 + lane];
            acc2 += h[(size_t)s2 * 64 + lane];
            acc3 += h[(size_t)s3 * 64 + lane];
        }
        for (; jj < m; jj++) {
            int s = __shfl(myidx, jj, 64);
            acc0 += h[(size_t)s * 64 + lane];
        }
    }
    agg[(size_t)w * 64 + lane] = acc0 + acc1 + acc2 + acc3;
}

// out[i][:] = (agg[i]/max(deg,1)) @ Wl + bias + hin[i] @ Wr, 2 nodes/thread
__global__ __launch_bounds__(256) void sage_matmul64(
    const float* __restrict__ agg, const float* __restrict__ hin,
    const int* __restrict__ rowptr, const float* __restrict__ Wl,
    const float* __restrict__ bias, const float* __restrict__ Wr,
    float* __restrict__ out, int n)
{
    __shared__ float4 sWl[64 * 16];
    __shared__ float4 sWr[64 * 16];
    for (int i = threadIdx.x; i < 64 * 16; i += 256) {
        sWl[i] = ((const float4*)Wl)[i];
        sWr[i] = ((const float4*)Wr)[i];
    }
    __syncthreads();

    int node0 = blockIdx.x * 512 + threadIdx.x;
    if (node0 >= n) return;
    int  node1 = node0 + 256;
    bool has1  = (node1 < n);
    int  n1    = has1 ? node1 : node0;

    float invd0 = 1.0f / fmaxf((float)(rowptr[node0 + 1] - rowptr[node0]), 1.0f);
    float invd1 = 1.0f / fmaxf((float)(rowptr[n1 + 1] - rowptr[n1]), 1.0f);

    float4 acc0[16], acc1[16];
#pragma unroll
    for (int cg = 0; cg < 16; cg++) {
        float4 bv = ((const float4*)bias)[cg];
        acc0[cg] = bv;
        acc1[cg] = bv;
    }

    const float4* ar0 = (const float4*)(agg + (size_t)node0 * 64);
    const float4* hr0 = (const float4*)(hin + (size_t)node0 * 64);
    const float4* ar1 = (const float4*)(agg + (size_t)n1 * 64);
    const float4* hr1 = (const float4*)(hin + (size_t)n1 * 64);

#pragma unroll 1   // keep body ~10KB: fits L1I; inner j/cg fully unrolled
    for (int k4 = 0; k4 < 16; k4++) {
        float4 a0 = ar0[k4], h0 = hr0[k4];
        float4 a1 = ar1[k4], h1 = hr1[k4];
        float aa0[4] = {a0.x, a0.y, a0.z, a0.w}, hh0[4] = {h0.x, h0.y, h0.z, h0.w};
        float aa1[4] = {a1.x, a1.y, a1.z, a1.w}, hh1[4] = {h1.x, h1.y, h1.z, h1.w};
#pragma unroll
        for (int j = 0; j < 4; j++) {
            float am0 = aa0[j] * invd0, hk0 = hh0[j];
            float am1 = aa1[j] * invd1, hk1 = hh1[j];
            int k = k4 * 4 + j;
#pragma unroll
            for (int cg = 0; cg < 16; cg++) {
                float4 wl = sWl[k * 16 + cg];
                float4 wr = sWr[k * 16 + cg];
                acc0[cg].x = fmaf(am0, wl.x, fmaf(hk0, wr.x, acc0[cg].x));
                acc0[cg].y = fmaf(am0, wl.y, fmaf(hk0, wr.y, acc0[cg].y));
                acc0[cg].z = fmaf(am0, wl.z, fmaf(hk0, wr.z, acc0[cg].z));
                acc0[cg].w = fmaf(am0, wl.w, fmaf(hk0, wr.w, acc0[cg].w));
                acc1[cg].x = fmaf(am1, wl.x, fmaf(hk1, wr.x, acc1[cg].x));
                acc1[cg].y = fmaf(am1, wl.y, fmaf(hk1, wr.y, acc1[cg].y));
                acc1[cg].z = fmaf(am1, wl.z, fmaf(hk1, wr.z, acc1[cg].z));
                acc1[cg].w = fmaf(am1, wl.w, fmaf(hk1, wr.w, acc1[cg].w));
            }
        }
    }
    float4* o0 = (float4*)(out + (size_t)node0 * 64);
#pragma unroll
    for (int cg = 0; cg < 16; cg++) o0[cg] = acc0[cg];
    if (has1) {
        float4* o1 = (float4*)(out + (size_t)node1 * 64);
#pragma unroll
        for (int cg = 0; cg < 16; cg++) o1[cg] = acc1[cg];
    }
}

// ---- BatchNorm ------------------------------------------------------------

__global__ __launch_bounds__(256) void bn_stats(const float* __restrict__ h,
                                                float* __restrict__ stats, size_t total)
{
    __shared__ float ls[64], lss[64];
    if (threadIdx.x < 64) { ls[threadIdx.x] = 0.f; lss[threadIdx.x] = 0.f; }
    __syncthreads();
    float s = 0.f, ss = 0.f;
    size_t stride = (size_t)gridDim.x * 256;
    for (size_t i = (size_t)blockIdx.x * 256 + threadIdx.x; i < total; i += stride) {
        float v = h[i];
        s += v;
        ss = fmaf(v, v, ss);
    }
    int c = threadIdx.x & 63;
    atomicAdd(&ls[c], s);
    atomicAdd(&lss[c], ss);
    __syncthreads();
    if (threadIdx.x < 64) {
        unsafeAtomicAdd(&stats[threadIdx.x], ls[threadIdx.x]);
        unsafeAtomicAdd(&stats[64 + threadIdx.x], lss[threadIdx.x]);
    }
}

__global__ __launch_bounds__(256) void bn_relu(float* __restrict__ h,
                                               const float* __restrict__ stats,
                                               const float* __restrict__ g,
                                               const float* __restrict__ be,
                                               float inv_n, size_t total)
{
    size_t i = (size_t)blockIdx.x * 256 + threadIdx.x;
    if (i >= total) return;
    int   c   = threadIdx.x & 63;
    float mu  = stats[c] * inv_n;
    float var = stats[64 + c] * inv_n - mu * mu;
    float sc  = g[c] / sqrtf(var + 1e-5f);
    float sh  = fmaf(-mu, sc, be[c]);
    h[i] = fmaxf(fmaf(h[i], sc, sh), 0.f);
}

// ---- pooling + heads ------------------------------------------------------

__global__ __launch_bounds__(256) void softmax_sum(const float* __restrict__ x,
                                                   float* __restrict__ sumexp, int n)
{
    float s = 0.f;
    int stride = gridDim.x * 256;
    for (int i = blockIdx.x * 256 + threadIdx.x; i < n; i += stride)
        s += expf(x[(size_t)i * 6 + 4]);
#pragma unroll
    for (int o = 32; o > 0; o >>= 1) s += __shfl_down(s, o, 64);
    __shared__ float wsum[4];
    if ((threadIdx.x & 63) == 0) wsum[threadIdx.x >> 6] = s;
    __syncthreads();
    if (threadIdx.x == 0)
        unsafeAtomicAdd(sumexp, wsum[0] + wsum[1] + wsum[2] + wsum[3]);
}

__global__ void seg_bounds(const int* __restrict__ batch, int* __restrict__ lb, int n)
{
    int b = threadIdx.x;
    if (b > 64) return;
    int lo = 0, hi = n;
    while (lo < hi) {
        int mid = (lo + hi) >> 1;
        if (batch[mid] < b) lo = mid + 1; else hi = mid;
    }
    lb[b] = lo;
}

__global__ __launch_bounds__(256) void pool_kernel(const float* __restrict__ h,
                                                   const float* __restrict__ x,
                                                   const int* __restrict__ lb,
                                                   const float* __restrict__ sumexp,
                                                   float* __restrict__ pool, int n)
{
    int b = blockIdx.x;
    int start = lb[b], end = lb[b + 1];
    int c = threadIdx.x & 63, grp = threadIdx.x >> 6;
    float inv_se = 1.0f / sumexp[0];
    float acc = 0.f;
    for (int i = start + grp; i < end; i += 4) {
        float w = expf(x[(size_t)i * 6 + 4]) * inv_se;
        acc = fmaf(h[(size_t)i * 64 + c], w, acc);
    }
    __shared__ float red[4][64];
    red[grp][c] = acc;
    __syncthreads();
    if (grp == 0) {
        float cnt = (float)(end - start);
        pool[b * 64 + c] = (red[0][c] + red[1][c] + red[2][c] + red[3][c]) / fmaxf(cnt, 1.0f);
    }
}

__global__ __launch_bounds__(64) void heads_kernel(
    const float* __restrict__ pool,
    const float* __restrict__ phW1, const float* __restrict__ phb1,
    const float* __restrict__ phW2, const float* __restrict__ phb2,
    const float* __restrict__ trW1, const float* __restrict__ trb1,
    const float* __restrict__ trW2, const float* __restrict__ trb2,
    float* __restrict__ out)
{
    int b = blockIdx.x, t = threadIdx.x;
    __shared__ float p[64], h1[32], h2[16];
    p[t] = pool[b * 64 + t];
    __syncthreads();
    if (t < 32) {
        float s = phb1[t];
        for (int k = 0; k < 64; k++) s = fmaf(p[k], phW1[k * 32 + t], s);
        h1[t] = fmaxf(s, 0.f);
    } else if (t < 48) {
        int tt = t - 32;
        float s = trb1[tt];
        for (int k = 0; k < 64; k++) s = fmaf(p[k], trW1[k * 16 + tt], s);
        h2[tt] = fmaxf(s, 0.f);
    }
    __syncthreads();
    if (t < 3) {
        float s = phb2[t];
        for (int k = 0; k < 32; k++) s = fmaf(h1[k], phW2[k * 3 + t], s);
        out[b * 3 + t] = s;
    } else if (t == 63) {
        float s = trb2[0];
        for (int k = 0; k < 16; k++) s = fmaf(h2[k], trW2[k], s);
        out[192 + b] = 1.0f / (1.0f + expf(-s));
    }
}

extern "C" void kernel_launch(void* const* d_in, const int* in_sizes, int n_in,
                              void* d_out, int out_size, void* d_ws, size_t ws_size,
                              hipStream_t stream)
{
    const float* x     = (const float*)d_in[0];
    const int*   ei    = (const int*)d_in[1];
    const int*   batch = (const int*)d_in[2];
    const float* W1l = (const float*)d_in[3];
    const float* b1  = (const float*)d_in[4];
    const float* W1r = (const float*)d_in[5];
    const float* W2l = (const float*)d_in[6];
    const float* b2  = (const float*)d_in[7];
    const float* W2r = (const float*)d_in[8];
    const float* W3l = (const float*)d_in[9];
    const float* b3  = (const float*)d_in[10];
    const float* W3r = (const float*)d_in[11];
    const float* g1  = (const float*)d_in[12];
    const float* be1 = (const float*)d_in[13];
    const float* g2  = (const float*)d_in[14];
    const float* be2 = (const float*)d_in[15];
    const float* g3  = (const float*)d_in[16];
    const float* be3 = (const float*)d_in[17];
    const float* phW1 = (const float*)d_in[18];
    const float* phb1 = (const float*)d_in[19];
    const float* phW2 = (const float*)d_in[20];
    const float* phb2 = (const float*)d_in[21];
    const float* trW1 = (const float*)d_in[22];
    const float* trb1 = (const float*)d_in[23];
    const float* trW2 = (const float*)d_in[24];
    const float* trb2 = (const float*)d_in[25];

    const int N = in_sizes[0] / 6;
    const int E = in_sizes[1] / 2;
    const int* src = ei;
    const int* dst = ei + E;

    const int NB    = (N + 255) >> 8;          // 391 buckets
    const int nBlkA = (E + EPB - 1) / EPB;     // 196 partition blocks

    float* ws = (float*)d_ws;
    const size_t N64 = (size_t)N * 64;
    float* agg      = ws;                          // N*64
    float* hA       = ws + N64;                    // N*64
    float* hB       = ws + 2 * N64;                // N*64
    int*   epck     = (int*)(ws + 3 * N64);        // E packed src|dl<<24
    int*   eidx     = epck + E;                    // E (CSR by dst)
    int*   blockBin = eidx + E;                    // nBlkA * NBIN
    // --- contiguous zero region: binTotal + stats[3][128] + sumexp ---
    int*   binTotal = blockBin + (size_t)nBlkA * NBIN;   // NBIN
    float* stats    = (float*)(binTotal + NBIN);   // 3 * 128
    float* sumexp   = stats + 384;                 // 1 (pad 4)
    // --- end zero region ---
    int*   binBase  = (int*)(sumexp + 4);          // NBIN + 1
    int*   rowptr   = binBase + NBIN + 1;          // N + 1
    int*   lb       = rowptr + N + 1;              // 65 (pad 72)
    float* pool     = (float*)(lb + 72);           // 64*64
    float* out      = (float*)d_out;

    const int nodeBlocks = (N + 255) / 256;
    const int waveNodeBlocks = (int)(((size_t)N * 64 + 255) / 256);
    const int ewBlocks  = (int)((N64 + 255) / 256);
    const int mm2Blocks = (N + 511) / 512;
    const float invN = 1.0f / (float)N;

    // ---- CSR build via bucket partition (no global write-amp) ----
    size_t zbytes = (char*)(sumexp + 4) - (char*)binTotal;
    hipMemsetAsync(binTotal, 0, zbytes, stream);
    bucket_hist<<<nBlkA, 256, 0, stream>>>(dst, blockBin, binTotal, E);
    bin_scan<<<1, NBIN, 0, stream>>>(binTotal, binBase, blockBin, rowptr + N, nBlkA);
    bucket_scatter<<<nBlkA, 256, 0, stream>>>(src, dst, blockBin, epck, E);
    csr_local<<<NB, 256, 0, stream>>>(epck, binBase, rowptr, eidx, N);

    // ---- layer 1 (6 ch, aggregation fused into matmul) ----
    sage1_fused<<<nodeBlocks, 256, 0, stream>>>(rowptr, eidx, x, W1l, b1, W1r, hA, N);
    bn_stats<<<1024, 256, 0, stream>>>(hA, stats, N64);
    bn_relu<<<ewBlocks, 256, 0, stream>>>(hA, stats, g1, be1, invN, N64);

    // ---- layer 2 ----
    aggpull64<<<waveNodeBlocks, 256, 0, stream>>>(rowptr, eidx, hA, agg, N);
    sage_matmul64<<<mm2Blocks, 256, 0, stream>>>(agg, hA, rowptr, W2l, b2, W2r, hB, N);
    bn_stats<<<1024, 256, 0, stream>>>(hB, stats + 128, N64);
    bn_relu<<<ewBlocks, 256, 0, stream>>>(hB, stats + 128, g2, be2, invN, N64);

    // ---- layer 3 ----
    aggpull64<<<waveNodeBlocks, 256, 0, stream>>>(rowptr, eidx, hB, agg, N);
    sage_matmul64<<<mm2Blocks, 256, 0, stream>>>(agg, hB, rowptr, W3l, b3, W3r, hA, N);
    bn_stats<<<1024, 256, 0, stream>>>(hA, stats + 256, N64);
    bn_relu<<<ewBlocks, 256, 0, stream>>>(hA, stats + 256, g3, be3, invN, N64);

    // ---- attention pooling + heads ----
    softmax_sum<<<256, 256, 0, stream>>>(x, sumexp, N);
    seg_bounds<<<1, 128, 0, stream>>>(batch, lb, N);
    pool_kernel<<<64, 256, 0, stream>>>(hA, x, lb, sumexp, pool, N);
    heads_kernel<<<64, 64, 0, stream>>>(pool, phW1, phb1, phW2, phb2,
                                        trW1, trb1, trW2, trb2, out);
}